// Round 1
// baseline (3194.970 us; speedup 1.0000x reference)
//
#include <hip/hip_runtime.h>
#include <math.h>

#define HIDDEN 2048
#define VOCAB  32000
#define BATCH  4
#define SEQ    2048
#define MROWS  (BATCH*SEQ)   /* 8192 */
#define IGNORE_INDEX (-100)

#define BM 128
#define BN 128
#define BK 64

typedef float floatx4 __attribute__((ext_vector_type(4)));
typedef short short8  __attribute__((ext_vector_type(8)));

__device__ __forceinline__ unsigned short f2bf(float f) {
    unsigned u = __float_as_uint(f);
    u += 0x7fffu + ((u >> 16) & 1u);   // round-to-nearest-even
    return (unsigned short)(u >> 16);
}

__device__ __forceinline__ unsigned pack2(float a, float b) {
    return (unsigned)f2bf(a) | ((unsigned)f2bf(b) << 16);
}

// ---- cast W [VOCAB, HIDDEN] fp32 -> bf16 ----------------------------------
__global__ void cast_w(const float* __restrict__ W, unsigned short* __restrict__ out) {
    const size_t g = (size_t)blockIdx.x * 256 + threadIdx.x;   // thread handles 8 elems
    const float4* src = (const float4*)(W + g * 8);
    float4 a = src[0];
    float4 b = src[1];
    uint4 pk;
    pk.x = pack2(a.x, a.y);
    pk.y = pack2(a.z, a.w);
    pk.z = pack2(b.x, b.y);
    pk.w = pack2(b.z, b.w);
    *(uint4*)(out + g * 8) = pk;
}

// ---- gather embed[ids] -> bf16 hidden [MROWS, HIDDEN] ---------------------
__global__ void gather_cast(const int* __restrict__ ids,
                            const float* __restrict__ embed,
                            unsigned short* __restrict__ out) {
    const int row = blockIdx.x;
    const int t   = threadIdx.x;       // 256 threads, 8 elems each: 2048/row
    const int e   = ids[row];
    const float4* src = (const float4*)(embed + (size_t)e * HIDDEN + t * 8);
    float4 a = src[0];
    float4 b = src[1];
    uint4 pk;
    pk.x = pack2(a.x, a.y);
    pk.y = pack2(a.z, a.w);
    pk.z = pack2(b.x, b.y);
    pk.w = pack2(b.z, b.w);
    *(uint4*)(out + (size_t)row * HIDDEN + t * 8) = pk;
}

// ---- GEMM: C[m][n] = sum_k A[m][k] * B[n][k]  (A=hidden bf16, B=W bf16) ---
// m97 structure: 128x128 tile, BK=64, global_load_lds width=16, 16x16x32 MFMA.
// XOR chunk swizzle: 16B chunk for (row, col8) lives at physical chunk
// row*8 + (col8 ^ (row&7)) -> ds_read_b128 fragment reads are conflict-free
// while the staging destination stays wave-uniform-base + lane*16.
__global__ __launch_bounds__(256)
void gemm_bt(const unsigned short* __restrict__ A,   // [MROWS, HIDDEN]
             const unsigned short* __restrict__ B,   // [VOCAB, HIDDEN]
             float* __restrict__ C)                  // [MROWS, VOCAB] at d_out+1
{
    __shared__ __attribute__((aligned(16))) char lds[32768];  // As 16K | Bs 16K
    const int tid = threadIdx.x;
    const int w   = tid >> 6;
    const int l   = tid & 63;
    const int mBase = blockIdx.x * BM;
    const int nBase = blockIdx.y * BN;
    const int wm = (w >> 1) * 64;   // wave row offset in tile
    const int wn = (w & 1) * 64;    // wave col offset in tile

    floatx4 acc[4][4] = {};

    // staging map: physical chunk p = i*256 + tid holds global (row, col8)
    int st_row[4], st_c8[4];
#pragma unroll
    for (int i = 0; i < 4; ++i) {
        int p = i * 256 + tid;
        st_row[i] = p >> 3;
        st_c8[i]  = (p & 7) ^ (st_row[i] & 7);
    }

    const unsigned short* Ab = A + (size_t)mBase * HIDDEN;
    const unsigned short* Bb = B + (size_t)nBase * HIDDEN;

    for (int k0 = 0; k0 < HIDDEN; k0 += BK) {
#pragma unroll
        for (int i = 0; i < 4; ++i) {
            const unsigned short* gp = Ab + st_row[i] * HIDDEN + k0 + st_c8[i] * 8;
            char* lp = lds + (i * 256 + w * 64) * 16;
            __builtin_amdgcn_global_load_lds(
                (const __attribute__((address_space(1))) void*)gp,
                (__attribute__((address_space(3))) void*)lp, 16, 0, 0);
        }
#pragma unroll
        for (int i = 0; i < 4; ++i) {
            const unsigned short* gp = Bb + st_row[i] * HIDDEN + k0 + st_c8[i] * 8;
            char* lp = lds + 16384 + (i * 256 + w * 64) * 16;
            __builtin_amdgcn_global_load_lds(
                (const __attribute__((address_space(1))) void*)gp,
                (__attribute__((address_space(3))) void*)lp, 16, 0, 0);
        }
        __syncthreads();

#pragma unroll
        for (int ks = 0; ks < 2; ++ks) {
            const int cb = ks * 4 + (l >> 4);   // col8 of this lane-quad
            short8 af[4], bf[4];
#pragma unroll
            for (int mt = 0; mt < 4; ++mt) {
                int r = wm + mt * 16 + (l & 15);
                int p = r * 8 + (cb ^ (r & 7));
                af[mt] = *(const short8*)(lds + p * 16);
            }
#pragma unroll
            for (int nt = 0; nt < 4; ++nt) {
                int r = wn + nt * 16 + (l & 15);
                int p = r * 8 + (cb ^ (r & 7));
                bf[nt] = *(const short8*)(lds + 16384 + p * 16);
            }
#pragma unroll
            for (int mt = 0; mt < 4; ++mt)
#pragma unroll
                for (int nt = 0; nt < 4; ++nt)
                    acc[mt][nt] = __builtin_amdgcn_mfma_f32_16x16x32_bf16(
                        af[mt], bf[nt], acc[mt][nt], 0, 0, 0);
        }
        __syncthreads();
    }

    // epilogue: C/D layout col=lane&15, row=(lane>>4)*4+reg
    const int rq = (l >> 4) * 4;
    const int cc = l & 15;
#pragma unroll
    for (int mt = 0; mt < 4; ++mt) {
#pragma unroll
        for (int nt = 0; nt < 4; ++nt) {
            float* cp = C + (size_t)(mBase + wm + mt * 16 + rq) * VOCAB
                          + (nBase + wn + nt * 16 + cc);
            floatx4 v = acc[mt][nt];
            cp[0 * (size_t)VOCAB] = v[0];
            cp[1 * (size_t)VOCAB] = v[1];
            cp[2 * (size_t)VOCAB] = v[2];
            cp[3 * (size_t)VOCAB] = v[3];
        }
    }
}

// ---- per-row online logsumexp + NLL --------------------------------------
__global__ void loss_kernel(const float* __restrict__ logits,  // d_out+1
                            const int* __restrict__ labels,
                            float* __restrict__ accum) {
    const int r = blockIdx.x;                    // 0..MROWS-1
    if ((r & (SEQ - 1)) == (SEQ - 1)) return;    // last position per batch: not used
    const int lab = labels[r + 1];
    if (lab == IGNORE_INDEX) return;
    const float* row = logits + (size_t)r * VOCAB;

    float m = -INFINITY, s = 0.0f;
    for (int i = threadIdx.x; i < VOCAB; i += 256) {   // 125 iters exactly
        float x  = row[i];
        float nm = fmaxf(m, x);
        s = s * __expf(m - nm) + __expf(x - nm);
        m = nm;
    }
#pragma unroll
    for (int off = 32; off > 0; off >>= 1) {
        float om = __shfl_xor(m, off, 64);
        float os = __shfl_xor(s, off, 64);
        float nm = fmaxf(m, om);
        s = s * __expf(m - nm) + os * __expf(om - nm);
        m = nm;
    }
    __shared__ float sm[4], ss[4];
    const int w = threadIdx.x >> 6, l = threadIdx.x & 63;
    if (l == 0) { sm[w] = m; ss[w] = s; }
    __syncthreads();
    if (threadIdx.x == 0) {
        float M = sm[0], S = ss[0];
#pragma unroll
        for (int i = 1; i < 4; ++i) {
            float nm = fmaxf(M, sm[i]);
            S = S * __expf(M - nm) + ss[i] * __expf(sm[i] - nm);
            M = nm;
        }
        float nll = (M + __logf(S)) - row[lab];
        atomicAdd(&accum[0], nll);
        atomicAdd(&accum[1], 1.0f);
    }
}

__global__ void finalize(const float* __restrict__ accum, float* __restrict__ out) {
    out[0] = accum[0] / fmaxf(accum[1], 1.0f);
}

extern "C" void kernel_launch(void* const* d_in, const int* in_sizes, int n_in,
                              void* d_out, int out_size, void* d_ws, size_t ws_size,
                              hipStream_t stream) {
    const int*   ids    = (const int*)d_in[0];
    const int*   labels = (const int*)d_in[1];
    const float* embed  = (const float*)d_in[2];
    const float* W      = (const float*)d_in[3];
    float* out = (float*)d_out;

    // workspace layout: W_bf16 (131072000 B) | hidden_bf16 (33554432 B) | accum (8 B)
    unsigned short* Wb = (unsigned short*)d_ws;
    unsigned short* Hb = (unsigned short*)((char*)d_ws + (size_t)VOCAB * HIDDEN * 2);
    float* accum = (float*)((char*)d_ws + (size_t)VOCAB * HIDDEN * 2 + (size_t)MROWS * HIDDEN * 2);

    hipMemsetAsync(accum, 0, 2 * sizeof(float), stream);
    cast_w<<<VOCAB * HIDDEN / (256 * 8), 256, 0, stream>>>(W, Wb);          // 32000 blocks
    gather_cast<<<MROWS, 256, 0, stream>>>(ids, embed, Hb);
    gemm_bt<<<dim3(MROWS / BM, VOCAB / BN), 256, 0, stream>>>(Hb, Wb, out + 1);
    loss_kernel<<<MROWS, 256, 0, stream>>>(out + 1, labels, accum);
    finalize<<<1, 1, 0, stream>>>(accum, out);
}